// Round 8
// baseline (130.272 us; speedup 1.0000x reference)
//
#include <hip/hip_runtime.h>
#include <math.h>

#define NEG_BIG -9.0e15f

typedef __attribute__((ext_vector_type(4))) float f32x4;
typedef __attribute__((ext_vector_type(8))) short bf16x8;
typedef __attribute__((ext_vector_type(4))) unsigned int u32x4;

// H^T[o][i] = sum_k X[i][k] * W[k][o]   (X:[1024,128], W:[128,128], HT:[128,1024])
__global__ __launch_bounds__(128) void gemm_xw_t(const float* __restrict__ X,
                                                 const float* __restrict__ W,
                                                 float* __restrict__ HT) {
  __shared__ float xrow[128];
  const int i = blockIdx.x;
  const int o = threadIdx.x;
  xrow[o] = X[(size_t)i * 128 + o];
  __syncthreads();
  float acc = 0.f;
#pragma unroll 16
  for (int k = 0; k < 128; ++k) acc = fmaf(xrow[k], W[(size_t)k * 128 + o], acc);
  HT[(size_t)o * 1024 + i] = acc;
}

#define DOT4(acc, hv, p) \
  acc = fmaf(hv.x, p.x, fmaf(hv.y, p.y, fmaf(hv.z, p.z, fmaf(hv.w, p.w, acc))));

// Fused GAT layer, 4 rows/block, 1024 threads, HT input (transposed).
// Phase 1 v3: h_i (all 4 rows, one uniform float4 -> s_load) + a (uniform
// scalar) in SGPRs; hv as coalesced float2; no ha_s LDS, unique (f,j) cover.
__global__ __launch_bounds__(1024, 4) void gat_attn(const float* __restrict__ HT,
                                                    const int* __restrict__ adj,
                                                    const float* __restrict__ a,
                                                    float* __restrict__ Xout) {
  __shared__ float ep2[2][4][1024];   // 32 KB: f-half partials [fh][row][j]
  __shared__ float e_s[4][1024];      // 16 KB: p (post-softmax weights)
  __shared__ float redm[4][4];
  __shared__ float redsum[4][4];
  __shared__ float inv_s[4];

  const int t = threadIdx.x;
  const int i0 = blockIdx.x * 4;
  const float2* __restrict__ HT2 = reinterpret_cast<const float2*>(HT);
  const float4* __restrict__ HT4 = reinterpret_cast<const float4*>(HT);

  // ---- phase 1: e[r][j] = sum_f |HT[f][j] - h_r[f]| * a[f] ----
  const int fh = t >> 9;        // 0..1 : f half within pass
  const int jp = t & 511;       // j pair index (2 j per thread)
  const int j0p = jp * 2;
  const int il = t >> 8;        // reduce-role row (0..3)
  const int j0 = (t & 255) * 4; // reduce-role j base

  float4 esum = {0.f, 0.f, 0.f, 0.f};
#pragma unroll
  for (int pass = 0; pass < 2; ++pass) {
    const int fb = pass * 64 + fh * 32;
    float a00 = 0.f, a01 = 0.f, a10 = 0.f, a11 = 0.f;
    float a20 = 0.f, a21 = 0.f, a30 = 0.f, a31 = 0.f;
#pragma unroll 8
    for (int ff = 0; ff < 32; ++ff) {
      const int f = fb + ff;
      const float4 hr = *reinterpret_cast<const float4*>(HT + ((size_t)f << 10) + i0);  // uniform -> s_load
      const float av = a[f];                                                            // uniform -> s_load
      const float2 hv = HT2[(f << 9) + jp];  // coalesced 8B/lane
      a00 = fmaf(fabsf(hv.x - hr.x), av, a00);
      a01 = fmaf(fabsf(hv.y - hr.x), av, a01);
      a10 = fmaf(fabsf(hv.x - hr.y), av, a10);
      a11 = fmaf(fabsf(hv.y - hr.y), av, a11);
      a20 = fmaf(fabsf(hv.x - hr.z), av, a20);
      a21 = fmaf(fabsf(hv.y - hr.z), av, a21);
      a30 = fmaf(fabsf(hv.x - hr.w), av, a30);
      a31 = fmaf(fabsf(hv.y - hr.w), av, a31);
    }
    *reinterpret_cast<float2*>(&ep2[fh][0][j0p]) = make_float2(a00, a01);
    *reinterpret_cast<float2*>(&ep2[fh][1][j0p]) = make_float2(a10, a11);
    *reinterpret_cast<float2*>(&ep2[fh][2][j0p]) = make_float2(a20, a21);
    *reinterpret_cast<float2*>(&ep2[fh][3][j0p]) = make_float2(a30, a31);
    __syncthreads();
    {
      const float4 s0 = *reinterpret_cast<const float4*>(&ep2[0][il][j0]);
      const float4 s1 = *reinterpret_cast<const float4*>(&ep2[1][il][j0]);
      esum.x += s0.x + s1.x;
      esum.y += s0.y + s1.y;
      esum.z += s0.z + s1.z;
      esum.w += s0.w + s1.w;
    }
    __syncthreads();
  }

  // ---- mask + relu ----
  float4 e;
  {
    const int4 ad = *reinterpret_cast<const int4*>(&adj[(size_t)(i0 + il) * 1024 + j0]);
    e.x = ad.x > 0 ? fmaxf(esum.x, 0.f) : NEG_BIG;
    e.y = ad.y > 0 ? fmaxf(esum.y, 0.f) : NEG_BIG;
    e.z = ad.z > 0 ? fmaxf(esum.z, 0.f) : NEG_BIG;
    e.w = ad.w > 0 ? fmaxf(esum.w, 0.f) : NEG_BIG;
  }

  // ---- softmax over j (4 waves per row) ----
  const int wq = (t >> 6) & 3;
  float m = fmaxf(fmaxf(e.x, e.y), fmaxf(e.z, e.w));
#pragma unroll
  for (int off = 32; off > 0; off >>= 1) m = fmaxf(m, __shfl_xor(m, off));
  if ((t & 63) == 0) redm[il][wq] = m;
  __syncthreads();
  m = fmaxf(fmaxf(redm[il][0], redm[il][1]), fmaxf(redm[il][2], redm[il][3]));
  float4 p;
  p.x = __expf(e.x - m);
  p.y = __expf(e.y - m);
  p.z = __expf(e.z - m);
  p.w = __expf(e.w - m);
  *reinterpret_cast<float4*>(&e_s[il][j0]) = p;
  float s = p.x + p.y + p.z + p.w;
#pragma unroll
  for (int off = 32; off > 0; off >>= 1) s += __shfl_xor(s, off);
  if ((t & 63) == 0) redsum[il][wq] = s;
  __syncthreads();
  if (t < 4) {
    const float ss = redsum[t][0] + redsum[t][1] + redsum[t][2] + redsum[t][3];
    inv_s[t] = 1.f / ss;
  }
  __syncthreads();

  // ---- phase 3: out[r][f] = relu(inv[r] * sum_j p[r][j] * HT[f][j]) ----
  const int w = t >> 6;
  const int l = t & 63;
  const int f0 = w * 8;
  float acc[8][4];
#pragma unroll
  for (int ff = 0; ff < 8; ++ff)
#pragma unroll
    for (int r = 0; r < 4; ++r) acc[ff][r] = 0.f;

#pragma unroll
  for (int jb = 0; jb < 4; ++jb) {
    const int j4 = jb * 64 + l;
    const float4 p0 = *reinterpret_cast<const float4*>(&e_s[0][j4 * 4]);
    const float4 p1 = *reinterpret_cast<const float4*>(&e_s[1][j4 * 4]);
    const float4 p2 = *reinterpret_cast<const float4*>(&e_s[2][j4 * 4]);
    const float4 p3 = *reinterpret_cast<const float4*>(&e_s[3][j4 * 4]);
#pragma unroll
    for (int ff = 0; ff < 8; ++ff) {
      const float4 hv = HT4[(f0 + ff) * 256 + j4];
      DOT4(acc[ff][0], hv, p0);
      DOT4(acc[ff][1], hv, p1);
      DOT4(acc[ff][2], hv, p2);
      DOT4(acc[ff][3], hv, p3);
    }
  }

  float v[32];
#pragma unroll
  for (int ff = 0; ff < 8; ++ff)
#pragma unroll
    for (int r = 0; r < 4; ++r) v[ff * 4 + r] = acc[ff][r];

#pragma unroll
  for (int step = 0; step < 5; ++step) {
    const int s2 = 1 << step;
    const bool hi = (l & s2) != 0;
#pragma unroll
    for (int k = 0; k < (32 >> (step + 1)); ++k) {
      const float x = v[2 * k];
      const float y = v[2 * k + 1];
      float tt = hi ? x : y;
      tt = __shfl_xor(tt, s2);
      v[k] = (hi ? y : x) + tt;
    }
  }
  float r = v[0] + __shfl_xor(v[0], 32);

  if (l < 32) {
    const int oidx = l & 31;
    const int ff = oidx >> 2;
    const int orow = oidx & 3;
    const float o = fmaxf(r * inv_s[orow], 0.f);
    Xout[(size_t)(i0 + orow) * 128 + f0 + ff] = o;
  }
}

// Symmetric EdgeGCN head via bf16-split MFMA (round-6 exact: 528 blocks,
// inline Wfc split, perm-packed A-prep, staged coalesced nontemporal stores).
__global__ __launch_bounds__(256) void edge_fc_mfma(const float* __restrict__ X,
                                                    const float* __restrict__ Wfc,
                                                    const float* __restrict__ bfc,
                                                    float* __restrict__ out) {
  __shared__ float xi_s[32][132];
  __shared__ float xj_s[32][132];
  __shared__ float ostage[4][256];

  const int t = threadIdx.x;
  const int bid = blockIdx.x;
  int jb = (int)((sqrtf(8.0f * (float)bid + 1.0f) - 1.0f) * 0.5f);
  int ib = bid - jb * (jb + 1) / 2;
  if (ib > jb) { jb++; ib = bid - jb * (jb + 1) / 2; }
  if (ib < 0) { jb--; ib = bid - jb * (jb + 1) / 2; }

  {
    const int r = t >> 3;
    const int c0 = (t & 7) * 16;
    const float4* gi = reinterpret_cast<const float4*>(X + (size_t)(ib * 32 + r) * 128 + c0);
    const float4* gj = reinterpret_cast<const float4*>(X + (size_t)(jb * 32 + r) * 128 + c0);
#pragma unroll
    for (int k = 0; k < 4; ++k) {
      *reinterpret_cast<float4*>(&xi_s[r][c0 + k * 4]) = gi[k];
      *reinterpret_cast<float4*>(&xj_s[r][c0 + k * 4]) = gj[k];
    }
  }

  const int w = t >> 6, lane = t & 63;
  const int col = lane & 15, kg = lane >> 4;

  // B fragments (Wfc split): k = c*32 + kg*8 + j
  bf16x8 bhi[4], blo[4];
#pragma unroll
  for (int c = 0; c < 4; ++c) {
    bf16x8 bh, bl;
#pragma unroll
    for (int j = 0; j < 8; ++j) {
      const float wv = Wfc[(c * 32 + kg * 8 + j) * 16 + col];
      const unsigned u = __builtin_bit_cast(unsigned, wv);
      const unsigned h = u & 0xffff0000u;
      const float lof = wv - __builtin_bit_cast(float, h);
      bh[j] = (short)(h >> 16);
      bl[j] = (short)(__builtin_bit_cast(unsigned, lof) >> 16);
    }
    bhi[c] = bh;
    blo[c] = bl;
  }
  const float bb = bfc[col];

  __syncthreads();

  // xj slice in registers: row j0+col, k-slice per lane
  const int j0 = (w & 1) * 16;
  const int ih = w >> 1;
  unsigned xjr[4][8];
#pragma unroll
  for (int c = 0; c < 4; ++c) {
    const float4 v0 = *reinterpret_cast<const float4*>(&xj_s[j0 + col][c * 32 + kg * 8]);
    const float4 v1 = *reinterpret_cast<const float4*>(&xj_s[j0 + col][c * 32 + kg * 8 + 4]);
    xjr[c][0] = __builtin_bit_cast(unsigned, v0.x);
    xjr[c][1] = __builtin_bit_cast(unsigned, v0.y);
    xjr[c][2] = __builtin_bit_cast(unsigned, v0.z);
    xjr[c][3] = __builtin_bit_cast(unsigned, v0.w);
    xjr[c][4] = __builtin_bit_cast(unsigned, v1.x);
    xjr[c][5] = __builtin_bit_cast(unsigned, v1.y);
    xjr[c][6] = __builtin_bit_cast(unsigned, v1.z);
    xjr[c][7] = __builtin_bit_cast(unsigned, v1.w);
  }

  const bool mirror = (ib != jb);

  for (int i = 0; i < 16; ++i) {
    const int li = ih * 16 + i;
    const int gi = ib * 32 + li;
    f32x4 acc = {bb, bb, bb, bb};
#pragma unroll
    for (int c = 0; c < 4; ++c) {
      const float4 v0 = *reinterpret_cast<const float4*>(&xi_s[li][c * 32 + kg * 8]);
      const float4 v1 = *reinterpret_cast<const float4*>(&xi_s[li][c * 32 + kg * 8 + 4]);
      unsigned xiv[8];
      xiv[0] = __builtin_bit_cast(unsigned, v0.x);
      xiv[1] = __builtin_bit_cast(unsigned, v0.y);
      xiv[2] = __builtin_bit_cast(unsigned, v0.z);
      xiv[3] = __builtin_bit_cast(unsigned, v0.w);
      xiv[4] = __builtin_bit_cast(unsigned, v1.x);
      xiv[5] = __builtin_bit_cast(unsigned, v1.y);
      xiv[6] = __builtin_bit_cast(unsigned, v1.z);
      xiv[7] = __builtin_bit_cast(unsigned, v1.w);
      u32x4 ahv, alv;
#pragma unroll
      for (int q = 0; q < 4; ++q) {
        const float d0 = __builtin_bit_cast(float, xjr[c][2 * q]) -
                         __builtin_bit_cast(float, xiv[2 * q]);
        const float d1 = __builtin_bit_cast(float, xjr[c][2 * q + 1]) -
                         __builtin_bit_cast(float, xiv[2 * q + 1]);
        const unsigned h0 = __builtin_bit_cast(unsigned, d0) & 0x7fff0000u;
        const unsigned h1 = __builtin_bit_cast(unsigned, d1) & 0x7fff0000u;
        const float lo0 = fabsf(d0) - __builtin_bit_cast(float, h0);
        const float lo1 = fabsf(d1) - __builtin_bit_cast(float, h1);
        ahv[q] = __builtin_amdgcn_perm(h1, h0, 0x07060302u);
        alv[q] = __builtin_amdgcn_perm(__builtin_bit_cast(unsigned, lo1),
                                       __builtin_bit_cast(unsigned, lo0), 0x07060302u);
      }
      const bf16x8 ah = __builtin_bit_cast(bf16x8, ahv);
      const bf16x8 al = __builtin_bit_cast(bf16x8, alv);
      acc = __builtin_amdgcn_mfma_f32_16x16x32_bf16(ah, bhi[c], acc, 0, 0, 0);
      acc = __builtin_amdgcn_mfma_f32_16x16x32_bf16(ah, blo[c], acc, 0, 0, 0);
      acc = __builtin_amdgcn_mfma_f32_16x16x32_bf16(al, bhi[c], acc, 0, 0, 0);
    }
#pragma unroll
    for (int r = 0; r < 4; ++r) ostage[w][(kg * 4 + r) * 16 + col] = acc[r];
    const f32x4 vv = *reinterpret_cast<const f32x4*>(&ostage[w][lane * 4]);
    const int jl = lane >> 2;
    const int c0 = (lane & 3) * 4;
    const int gj = jb * 32 + j0 + jl;
    __builtin_nontemporal_store(vv, reinterpret_cast<f32x4*>(out + ((size_t)gi * 1024 + gj) * 16 + c0));
    if (mirror)
      __builtin_nontemporal_store(vv, reinterpret_cast<f32x4*>(out + ((size_t)gj * 1024 + gi) * 16 + c0));
  }
}

extern "C" void kernel_launch(void* const* d_in, const int* in_sizes, int n_in,
                              void* d_out, int out_size, void* d_ws, size_t ws_size,
                              hipStream_t stream) {
  const float* feat = (const float*)d_in[0];
  const int* adj = (const int*)d_in[1];
  const float* W1 = (const float*)d_in[2];
  const float* a1 = (const float*)d_in[3];
  const float* W2 = (const float*)d_in[4];
  const float* a2 = (const float*)d_in[5];
  const float* W3 = (const float*)d_in[6];
  const float* a3 = (const float*)d_in[7];
  const float* Wfc = (const float*)d_in[8];
  const float* bfc = (const float*)d_in[9];
  float* out = (float*)d_out;

  float* ht = (float*)d_ws;        // 1024*128 (transposed H)
  float* xA = ht + 131072;         // 1024*128
  float* xB = xA + 131072;         // 1024*128

  gemm_xw_t<<<1024, 128, 0, stream>>>(feat, W1, ht);
  gat_attn<<<256, 1024, 0, stream>>>(ht, adj, a1, xA);
  gemm_xw_t<<<1024, 128, 0, stream>>>(xA, W2, ht);
  gat_attn<<<256, 1024, 0, stream>>>(ht, adj, a2, xB);
  gemm_xw_t<<<1024, 128, 0, stream>>>(xB, W3, ht);
  gat_attn<<<256, 1024, 0, stream>>>(ht, adj, a3, xA);
  edge_fc_mfma<<<528, 256, 0, stream>>>(xA, Wfc, bfc, out);
}

// Round 9
// 104.879 us; speedup vs baseline: 1.2421x; 1.2421x over previous
//
#include <hip/hip_runtime.h>
#include <math.h>

#define NEG_BIG -9.0e15f

typedef __attribute__((ext_vector_type(4))) float f32x4;
typedef __attribute__((ext_vector_type(8))) short bf16x8;
typedef __attribute__((ext_vector_type(4))) unsigned int u32x4;

// H^T[o][i] = sum_k X[i][k] * W[k][o]   (X:[1024,128], W:[128,128], HT:[128,1024])
__global__ __launch_bounds__(128) void gemm_xw_t(const float* __restrict__ X,
                                                 const float* __restrict__ W,
                                                 float* __restrict__ HT) {
  __shared__ float xrow[128];
  const int i = blockIdx.x;
  const int o = threadIdx.x;
  xrow[o] = X[(size_t)i * 128 + o];
  __syncthreads();
  float acc = 0.f;
#pragma unroll 16
  for (int k = 0; k < 128; ++k) acc = fmaf(xrow[k], W[(size_t)k * 128 + o], acc);
  HT[(size_t)o * 1024 + i] = acc;
}

#define DOT4(acc, hv, p) \
  acc = fmaf(hv.x, p.x, fmaf(hv.y, p.y, fmaf(hv.z, p.z, fmaf(hv.w, p.w, acc))));

#define ABSFMA4R(accR, hv, hs, av)                  \
  accR.x = fmaf(fabsf(hv.x - hs), av, accR.x);      \
  accR.y = fmaf(fabsf(hv.y - hs), av, accR.y);      \
  accR.z = fmaf(fabsf(hv.z - hs), av, accR.z);      \
  accR.w = fmaf(fabsf(hv.w - hs), av, accR.w);

// Fused GAT layer, 4 rows/block, 1024 threads, HT input (transposed).
// P1 v4: h for all 4 rows packed as float4 in LDS (one b128 broadcast per f),
// each thread covers 4 rows x 4 j -> unique hv coverage, single partial pass.
__global__ __launch_bounds__(1024, 4) void gat_attn(const float* __restrict__ HT,
                                                    const int* __restrict__ adj,
                                                    const float* __restrict__ a,
                                                    float* __restrict__ Xout) {
  __shared__ float4 ep4[4][4][256];   // 64 KB: [fq][row][jt] (float4 over j)
  __shared__ float e_s[4][1024];      // 16 KB: p (post-softmax weights)
  __shared__ float4 h4_s[128];        // 2 KB: h_i[f] for the 4 rows
  __shared__ float a_s[128];
  __shared__ float redm[4][4];
  __shared__ float redsum[4][4];
  __shared__ float inv_s[4];

  const int t = threadIdx.x;
  const int i0 = blockIdx.x * 4;
  const float4* __restrict__ HT4 = reinterpret_cast<const float4*>(HT);

  if (t < 128) {
    h4_s[t] = *reinterpret_cast<const float4*>(HT + ((size_t)t << 10) + i0);
    a_s[t] = a[t];
  }
  __syncthreads();

  const int fq = t >> 8;        // 0..3 : f quarter
  const int jt = t & 255;       // float4 j-group
  const int il = t >> 8;        // reduce-role row (0..3)
  const int j0 = jt * 4;

  // ---- phase 1: partials for 4 rows x 4 j over this thread's 32 f ----
  float4 ac0 = {0.f, 0.f, 0.f, 0.f};
  float4 ac1 = {0.f, 0.f, 0.f, 0.f};
  float4 ac2 = {0.f, 0.f, 0.f, 0.f};
  float4 ac3 = {0.f, 0.f, 0.f, 0.f};
#pragma unroll 8
  for (int ff = 0; ff < 32; ++ff) {
    const int f = fq * 32 + ff;
    const float4 hv = HT4[f * 256 + jt];   // coalesced, unique (f,jt)
    const float4 h4 = h4_s[f];             // b128 broadcast
    const float av = a_s[f];               // b32 broadcast
    ABSFMA4R(ac0, hv, h4.x, av);
    ABSFMA4R(ac1, hv, h4.y, av);
    ABSFMA4R(ac2, hv, h4.z, av);
    ABSFMA4R(ac3, hv, h4.w, av);
  }
  ep4[fq][0][jt] = ac0;
  ep4[fq][1][jt] = ac1;
  ep4[fq][2][jt] = ac2;
  ep4[fq][3][jt] = ac3;
  __syncthreads();

  float4 esum;
  {
    const float4 s0 = ep4[0][il][jt];
    const float4 s1 = ep4[1][il][jt];
    const float4 s2 = ep4[2][il][jt];
    const float4 s3 = ep4[3][il][jt];
    esum.x = (s0.x + s1.x) + (s2.x + s3.x);
    esum.y = (s0.y + s1.y) + (s2.y + s3.y);
    esum.z = (s0.z + s1.z) + (s2.z + s3.z);
    esum.w = (s0.w + s1.w) + (s2.w + s3.w);
  }

  // ---- mask + relu ----
  float4 e;
  {
    const int4 ad = *reinterpret_cast<const int4*>(&adj[(size_t)(i0 + il) * 1024 + j0]);
    e.x = ad.x > 0 ? fmaxf(esum.x, 0.f) : NEG_BIG;
    e.y = ad.y > 0 ? fmaxf(esum.y, 0.f) : NEG_BIG;
    e.z = ad.z > 0 ? fmaxf(esum.z, 0.f) : NEG_BIG;
    e.w = ad.w > 0 ? fmaxf(esum.w, 0.f) : NEG_BIG;
  }

  // ---- softmax over j (4 waves per row) ----
  const int wq = (t >> 6) & 3;
  float m = fmaxf(fmaxf(e.x, e.y), fmaxf(e.z, e.w));
#pragma unroll
  for (int off = 32; off > 0; off >>= 1) m = fmaxf(m, __shfl_xor(m, off));
  if ((t & 63) == 0) redm[il][wq] = m;
  __syncthreads();
  m = fmaxf(fmaxf(redm[il][0], redm[il][1]), fmaxf(redm[il][2], redm[il][3]));
  float4 p;
  p.x = __expf(e.x - m);
  p.y = __expf(e.y - m);
  p.z = __expf(e.z - m);
  p.w = __expf(e.w - m);
  *reinterpret_cast<float4*>(&e_s[il][j0]) = p;
  float s = p.x + p.y + p.z + p.w;
#pragma unroll
  for (int off = 32; off > 0; off >>= 1) s += __shfl_xor(s, off);
  if ((t & 63) == 0) redsum[il][wq] = s;
  __syncthreads();
  if (t < 4) {
    const float ss = redsum[t][0] + redsum[t][1] + redsum[t][2] + redsum[t][3];
    inv_s[t] = 1.f / ss;
  }
  __syncthreads();

  // ---- phase 3: out[r][f] = relu(inv[r] * sum_j p[r][j] * HT[f][j]) ----
  const int w = t >> 6;
  const int l = t & 63;
  const int f0 = w * 8;
  float acc[8][4];
#pragma unroll
  for (int ff = 0; ff < 8; ++ff)
#pragma unroll
    for (int r = 0; r < 4; ++r) acc[ff][r] = 0.f;

#pragma unroll
  for (int jb = 0; jb < 4; ++jb) {
    const int j4 = jb * 64 + l;
    const float4 p0 = *reinterpret_cast<const float4*>(&e_s[0][j4 * 4]);
    const float4 p1 = *reinterpret_cast<const float4*>(&e_s[1][j4 * 4]);
    const float4 p2 = *reinterpret_cast<const float4*>(&e_s[2][j4 * 4]);
    const float4 p3 = *reinterpret_cast<const float4*>(&e_s[3][j4 * 4]);
#pragma unroll
    for (int ff = 0; ff < 8; ++ff) {
      const float4 hv = HT4[(f0 + ff) * 256 + j4];
      DOT4(acc[ff][0], hv, p0);
      DOT4(acc[ff][1], hv, p1);
      DOT4(acc[ff][2], hv, p2);
      DOT4(acc[ff][3], hv, p3);
    }
  }

  float v[32];
#pragma unroll
  for (int ff = 0; ff < 8; ++ff)
#pragma unroll
    for (int r = 0; r < 4; ++r) v[ff * 4 + r] = acc[ff][r];

#pragma unroll
  for (int step = 0; step < 5; ++step) {
    const int s2 = 1 << step;
    const bool hi = (l & s2) != 0;
#pragma unroll
    for (int k = 0; k < (32 >> (step + 1)); ++k) {
      const float x = v[2 * k];
      const float y = v[2 * k + 1];
      float tt = hi ? x : y;
      tt = __shfl_xor(tt, s2);
      v[k] = (hi ? y : x) + tt;
    }
  }
  float r = v[0] + __shfl_xor(v[0], 32);

  if (l < 32) {
    const int oidx = l & 31;
    const int ff = oidx >> 2;
    const int orow = oidx & 3;
    const float o = fmaxf(r * inv_s[orow], 0.f);
    Xout[(size_t)(i0 + orow) * 128 + f0 + ff] = o;
  }
}

// Symmetric EdgeGCN head via bf16-split MFMA (round-6 exact: 528 blocks,
// inline Wfc split, perm-packed A-prep, staged coalesced nontemporal stores).
__global__ __launch_bounds__(256) void edge_fc_mfma(const float* __restrict__ X,
                                                    const float* __restrict__ Wfc,
                                                    const float* __restrict__ bfc,
                                                    float* __restrict__ out) {
  __shared__ float xi_s[32][132];
  __shared__ float xj_s[32][132];
  __shared__ float ostage[4][256];

  const int t = threadIdx.x;
  const int bid = blockIdx.x;
  int jb = (int)((sqrtf(8.0f * (float)bid + 1.0f) - 1.0f) * 0.5f);
  int ib = bid - jb * (jb + 1) / 2;
  if (ib > jb) { jb++; ib = bid - jb * (jb + 1) / 2; }
  if (ib < 0) { jb--; ib = bid - jb * (jb + 1) / 2; }

  {
    const int r = t >> 3;
    const int c0 = (t & 7) * 16;
    const float4* gi = reinterpret_cast<const float4*>(X + (size_t)(ib * 32 + r) * 128 + c0);
    const float4* gj = reinterpret_cast<const float4*>(X + (size_t)(jb * 32 + r) * 128 + c0);
#pragma unroll
    for (int k = 0; k < 4; ++k) {
      *reinterpret_cast<float4*>(&xi_s[r][c0 + k * 4]) = gi[k];
      *reinterpret_cast<float4*>(&xj_s[r][c0 + k * 4]) = gj[k];
    }
  }

  const int w = t >> 6, lane = t & 63;
  const int col = lane & 15, kg = lane >> 4;

  // B fragments (Wfc split): k = c*32 + kg*8 + j
  bf16x8 bhi[4], blo[4];
#pragma unroll
  for (int c = 0; c < 4; ++c) {
    bf16x8 bh, bl;
#pragma unroll
    for (int j = 0; j < 8; ++j) {
      const float wv = Wfc[(c * 32 + kg * 8 + j) * 16 + col];
      const unsigned u = __builtin_bit_cast(unsigned, wv);
      const unsigned h = u & 0xffff0000u;
      const float lof = wv - __builtin_bit_cast(float, h);
      bh[j] = (short)(h >> 16);
      bl[j] = (short)(__builtin_bit_cast(unsigned, lof) >> 16);
    }
    bhi[c] = bh;
    blo[c] = bl;
  }
  const float bb = bfc[col];

  __syncthreads();

  // xj slice in registers: row j0+col, k-slice per lane
  const int j0 = (w & 1) * 16;
  const int ih = w >> 1;
  unsigned xjr[4][8];
#pragma unroll
  for (int c = 0; c < 4; ++c) {
    const float4 v0 = *reinterpret_cast<const float4*>(&xj_s[j0 + col][c * 32 + kg * 8]);
    const float4 v1 = *reinterpret_cast<const float4*>(&xj_s[j0 + col][c * 32 + kg * 8 + 4]);
    xjr[c][0] = __builtin_bit_cast(unsigned, v0.x);
    xjr[c][1] = __builtin_bit_cast(unsigned, v0.y);
    xjr[c][2] = __builtin_bit_cast(unsigned, v0.z);
    xjr[c][3] = __builtin_bit_cast(unsigned, v0.w);
    xjr[c][4] = __builtin_bit_cast(unsigned, v1.x);
    xjr[c][5] = __builtin_bit_cast(unsigned, v1.y);
    xjr[c][6] = __builtin_bit_cast(unsigned, v1.z);
    xjr[c][7] = __builtin_bit_cast(unsigned, v1.w);
  }

  const bool mirror = (ib != jb);

  for (int i = 0; i < 16; ++i) {
    const int li = ih * 16 + i;
    const int gi = ib * 32 + li;
    f32x4 acc = {bb, bb, bb, bb};
#pragma unroll
    for (int c = 0; c < 4; ++c) {
      const float4 v0 = *reinterpret_cast<const float4*>(&xi_s[li][c * 32 + kg * 8]);
      const float4 v1 = *reinterpret_cast<const float4*>(&xi_s[li][c * 32 + kg * 8 + 4]);
      unsigned xiv[8];
      xiv[0] = __builtin_bit_cast(unsigned, v0.x);
      xiv[1] = __builtin_bit_cast(unsigned, v0.y);
      xiv[2] = __builtin_bit_cast(unsigned, v0.z);
      xiv[3] = __builtin_bit_cast(unsigned, v0.w);
      xiv[4] = __builtin_bit_cast(unsigned, v1.x);
      xiv[5] = __builtin_bit_cast(unsigned, v1.y);
      xiv[6] = __builtin_bit_cast(unsigned, v1.z);
      xiv[7] = __builtin_bit_cast(unsigned, v1.w);
      u32x4 ahv, alv;
#pragma unroll
      for (int q = 0; q < 4; ++q) {
        const float d0 = __builtin_bit_cast(float, xjr[c][2 * q]) -
                         __builtin_bit_cast(float, xiv[2 * q]);
        const float d1 = __builtin_bit_cast(float, xjr[c][2 * q + 1]) -
                         __builtin_bit_cast(float, xiv[2 * q + 1]);
        const unsigned h0 = __builtin_bit_cast(unsigned, d0) & 0x7fff0000u;
        const unsigned h1 = __builtin_bit_cast(unsigned, d1) & 0x7fff0000u;
        const float lo0 = fabsf(d0) - __builtin_bit_cast(float, h0);
        const float lo1 = fabsf(d1) - __builtin_bit_cast(float, h1);
        ahv[q] = __builtin_amdgcn_perm(h1, h0, 0x07060302u);
        alv[q] = __builtin_amdgcn_perm(__builtin_bit_cast(unsigned, lo1),
                                       __builtin_bit_cast(unsigned, lo0), 0x07060302u);
      }
      const bf16x8 ah = __builtin_bit_cast(bf16x8, ahv);
      const bf16x8 al = __builtin_bit_cast(bf16x8, alv);
      acc = __builtin_amdgcn_mfma_f32_16x16x32_bf16(ah, bhi[c], acc, 0, 0, 0);
      acc = __builtin_amdgcn_mfma_f32_16x16x32_bf16(ah, blo[c], acc, 0, 0, 0);
      acc = __builtin_amdgcn_mfma_f32_16x16x32_bf16(al, bhi[c], acc, 0, 0, 0);
    }
#pragma unroll
    for (int r = 0; r < 4; ++r) ostage[w][(kg * 4 + r) * 16 + col] = acc[r];
    const f32x4 vv = *reinterpret_cast<const f32x4*>(&ostage[w][lane * 4]);
    const int jl = lane >> 2;
    const int c0 = (lane & 3) * 4;
    const int gj = jb * 32 + j0 + jl;
    __builtin_nontemporal_store(vv, reinterpret_cast<f32x4*>(out + ((size_t)gi * 1024 + gj) * 16 + c0));
    if (mirror)
      __builtin_nontemporal_store(vv, reinterpret_cast<f32x4*>(out + ((size_t)gj * 1024 + gi) * 16 + c0));
  }
}

extern "C" void kernel_launch(void* const* d_in, const int* in_sizes, int n_in,
                              void* d_out, int out_size, void* d_ws, size_t ws_size,
                              hipStream_t stream) {
  const float* feat = (const float*)d_in[0];
  const int* adj = (const int*)d_in[1];
  const float* W1 = (const float*)d_in[2];
  const float* a1 = (const float*)d_in[3];
  const float* W2 = (const float*)d_in[4];
  const float* a2 = (const float*)d_in[5];
  const float* W3 = (const float*)d_in[6];
  const float* a3 = (const float*)d_in[7];
  const float* Wfc = (const float*)d_in[8];
  const float* bfc = (const float*)d_in[9];
  float* out = (float*)d_out;

  float* ht = (float*)d_ws;        // 1024*128 (transposed H)
  float* xA = ht + 131072;         // 1024*128
  float* xB = xA + 131072;         // 1024*128

  gemm_xw_t<<<1024, 128, 0, stream>>>(feat, W1, ht);
  gat_attn<<<256, 1024, 0, stream>>>(ht, adj, a1, xA);
  gemm_xw_t<<<1024, 128, 0, stream>>>(xA, W2, ht);
  gat_attn<<<256, 1024, 0, stream>>>(ht, adj, a2, xB);
  gemm_xw_t<<<1024, 128, 0, stream>>>(xB, W3, ht);
  gat_attn<<<256, 1024, 0, stream>>>(ht, adj, a3, xA);
  edge_fc_mfma<<<528, 256, 0, stream>>>(xA, Wfc, bfc, out);
}

// Round 10
// 102.111 us; speedup vs baseline: 1.2758x; 1.0271x over previous
//
#include <hip/hip_runtime.h>
#include <math.h>

#define NEG_BIG -9.0e15f

typedef __attribute__((ext_vector_type(4))) float f32x4;
typedef __attribute__((ext_vector_type(8))) short bf16x8;
typedef __attribute__((ext_vector_type(4))) unsigned int u32x4;

// H^T[o][i] = sum_k X[i][k] * W[k][o]   (X:[1024,128], W:[128,128], HT:[128,1024])
__global__ __launch_bounds__(128) void gemm_xw_t(const float* __restrict__ X,
                                                 const float* __restrict__ W,
                                                 float* __restrict__ HT) {
  __shared__ float xrow[128];
  const int i = blockIdx.x;
  const int o = threadIdx.x;
  xrow[o] = X[(size_t)i * 128 + o];
  __syncthreads();
  float acc = 0.f;
#pragma unroll 16
  for (int k = 0; k < 128; ++k) acc = fmaf(xrow[k], W[(size_t)k * 128 + o], acc);
  HT[(size_t)o * 1024 + i] = acc;
}

#define DOT4(acc, hv, p) \
  acc = fmaf(hv.x, p.x, fmaf(hv.y, p.y, fmaf(hv.z, p.z, fmaf(hv.w, p.w, acc))));

#define ABSFMA4R(accR, hv, hs, av)                  \
  accR.x = fmaf(fabsf(hv.x - hs), av, accR.x);      \
  accR.y = fmaf(fabsf(hv.y - hs), av, accR.y);      \
  accR.z = fmaf(fabsf(hv.z - hs), av, accR.z);      \
  accR.w = fmaf(fabsf(hv.w - hs), av, accR.w);

// Fused GAT layer, 4 rows/block, 1024 threads, HT input (transposed).
// (round-9 version, measured best) -- UNCHANGED
__global__ __launch_bounds__(1024, 4) void gat_attn(const float* __restrict__ HT,
                                                    const int* __restrict__ adj,
                                                    const float* __restrict__ a,
                                                    float* __restrict__ Xout) {
  __shared__ float4 ep4[4][4][256];   // 64 KB: [fq][row][jt] (float4 over j)
  __shared__ float e_s[4][1024];      // 16 KB: p (post-softmax weights)
  __shared__ float4 h4_s[128];        // 2 KB: h_i[f] for the 4 rows
  __shared__ float a_s[128];
  __shared__ float redm[4][4];
  __shared__ float redsum[4][4];
  __shared__ float inv_s[4];

  const int t = threadIdx.x;
  const int i0 = blockIdx.x * 4;
  const float4* __restrict__ HT4 = reinterpret_cast<const float4*>(HT);

  if (t < 128) {
    h4_s[t] = *reinterpret_cast<const float4*>(HT + ((size_t)t << 10) + i0);
    a_s[t] = a[t];
  }
  __syncthreads();

  const int fq = t >> 8;        // 0..3 : f quarter
  const int jt = t & 255;       // float4 j-group
  const int il = t >> 8;        // reduce-role row (0..3)
  const int j0 = jt * 4;

  float4 ac0 = {0.f, 0.f, 0.f, 0.f};
  float4 ac1 = {0.f, 0.f, 0.f, 0.f};
  float4 ac2 = {0.f, 0.f, 0.f, 0.f};
  float4 ac3 = {0.f, 0.f, 0.f, 0.f};
#pragma unroll 8
  for (int ff = 0; ff < 32; ++ff) {
    const int f = fq * 32 + ff;
    const float4 hv = HT4[f * 256 + jt];   // coalesced, unique (f,jt)
    const float4 h4 = h4_s[f];             // b128 broadcast
    const float av = a_s[f];               // b32 broadcast
    ABSFMA4R(ac0, hv, h4.x, av);
    ABSFMA4R(ac1, hv, h4.y, av);
    ABSFMA4R(ac2, hv, h4.z, av);
    ABSFMA4R(ac3, hv, h4.w, av);
  }
  ep4[fq][0][jt] = ac0;
  ep4[fq][1][jt] = ac1;
  ep4[fq][2][jt] = ac2;
  ep4[fq][3][jt] = ac3;
  __syncthreads();

  float4 esum;
  {
    const float4 s0 = ep4[0][il][jt];
    const float4 s1 = ep4[1][il][jt];
    const float4 s2 = ep4[2][il][jt];
    const float4 s3 = ep4[3][il][jt];
    esum.x = (s0.x + s1.x) + (s2.x + s3.x);
    esum.y = (s0.y + s1.y) + (s2.y + s3.y);
    esum.z = (s0.z + s1.z) + (s2.z + s3.z);
    esum.w = (s0.w + s1.w) + (s2.w + s3.w);
  }

  float4 e;
  {
    const int4 ad = *reinterpret_cast<const int4*>(&adj[(size_t)(i0 + il) * 1024 + j0]);
    e.x = ad.x > 0 ? fmaxf(esum.x, 0.f) : NEG_BIG;
    e.y = ad.y > 0 ? fmaxf(esum.y, 0.f) : NEG_BIG;
    e.z = ad.z > 0 ? fmaxf(esum.z, 0.f) : NEG_BIG;
    e.w = ad.w > 0 ? fmaxf(esum.w, 0.f) : NEG_BIG;
  }

  const int wq = (t >> 6) & 3;
  float m = fmaxf(fmaxf(e.x, e.y), fmaxf(e.z, e.w));
#pragma unroll
  for (int off = 32; off > 0; off >>= 1) m = fmaxf(m, __shfl_xor(m, off));
  if ((t & 63) == 0) redm[il][wq] = m;
  __syncthreads();
  m = fmaxf(fmaxf(redm[il][0], redm[il][1]), fmaxf(redm[il][2], redm[il][3]));
  float4 p;
  p.x = __expf(e.x - m);
  p.y = __expf(e.y - m);
  p.z = __expf(e.z - m);
  p.w = __expf(e.w - m);
  *reinterpret_cast<float4*>(&e_s[il][j0]) = p;
  float s = p.x + p.y + p.z + p.w;
#pragma unroll
  for (int off = 32; off > 0; off >>= 1) s += __shfl_xor(s, off);
  if ((t & 63) == 0) redsum[il][wq] = s;
  __syncthreads();
  if (t < 4) {
    const float ss = redsum[t][0] + redsum[t][1] + redsum[t][2] + redsum[t][3];
    inv_s[t] = 1.f / ss;
  }
  __syncthreads();

  const int w = t >> 6;
  const int l = t & 63;
  const int f0 = w * 8;
  float acc[8][4];
#pragma unroll
  for (int ff = 0; ff < 8; ++ff)
#pragma unroll
    for (int r = 0; r < 4; ++r) acc[ff][r] = 0.f;

#pragma unroll
  for (int jb = 0; jb < 4; ++jb) {
    const int j4 = jb * 64 + l;
    const float4 p0 = *reinterpret_cast<const float4*>(&e_s[0][j4 * 4]);
    const float4 p1 = *reinterpret_cast<const float4*>(&e_s[1][j4 * 4]);
    const float4 p2 = *reinterpret_cast<const float4*>(&e_s[2][j4 * 4]);
    const float4 p3 = *reinterpret_cast<const float4*>(&e_s[3][j4 * 4]);
#pragma unroll
    for (int ff = 0; ff < 8; ++ff) {
      const float4 hv = HT4[(f0 + ff) * 256 + j4];
      DOT4(acc[ff][0], hv, p0);
      DOT4(acc[ff][1], hv, p1);
      DOT4(acc[ff][2], hv, p2);
      DOT4(acc[ff][3], hv, p3);
    }
  }

  float v[32];
#pragma unroll
  for (int ff = 0; ff < 8; ++ff)
#pragma unroll
    for (int r = 0; r < 4; ++r) v[ff * 4 + r] = acc[ff][r];

#pragma unroll
  for (int step = 0; step < 5; ++step) {
    const int s2 = 1 << step;
    const bool hi = (l & s2) != 0;
#pragma unroll
    for (int k = 0; k < (32 >> (step + 1)); ++k) {
      const float x = v[2 * k];
      const float y = v[2 * k + 1];
      float tt = hi ? x : y;
      tt = __shfl_xor(tt, s2);
      v[k] = (hi ? y : x) + tt;
    }
  }
  float r = v[0] + __shfl_xor(v[0], 32);

  if (l < 32) {
    const int oidx = l & 31;
    const int ff = oidx >> 2;
    const int orow = oidx & 3;
    const float o = fmaxf(r * inv_s[orow], 0.f);
    Xout[(size_t)(i0 + orow) * 128 + f0 + ff] = o;
  }
}

// EdgeGCN head via bf16-split MFMA. Full grid (1024 blocks, one 32x32-pair
// tile each): no mirror scatter -- every store is a coalesced 1KB wave-store.
__global__ __launch_bounds__(256) void edge_fc_mfma(const float* __restrict__ X,
                                                    const float* __restrict__ Wfc,
                                                    const float* __restrict__ bfc,
                                                    float* __restrict__ out) {
  __shared__ float xi_s[32][132];
  __shared__ float xj_s[32][132];
  __shared__ float ostage[4][256];

  const int t = threadIdx.x;
  const int ib = blockIdx.x >> 5;
  const int jb = blockIdx.x & 31;

  {
    const int r = t >> 3;
    const int c0 = (t & 7) * 16;
    const float4* gi = reinterpret_cast<const float4*>(X + (size_t)(ib * 32 + r) * 128 + c0);
    const float4* gj = reinterpret_cast<const float4*>(X + (size_t)(jb * 32 + r) * 128 + c0);
#pragma unroll
    for (int k = 0; k < 4; ++k) {
      *reinterpret_cast<float4*>(&xi_s[r][c0 + k * 4]) = gi[k];
      *reinterpret_cast<float4*>(&xj_s[r][c0 + k * 4]) = gj[k];
    }
  }

  const int w = t >> 6, lane = t & 63;
  const int col = lane & 15, kg = lane >> 4;

  // B fragments (Wfc split): k = c*32 + kg*8 + j
  bf16x8 bhi[4], blo[4];
#pragma unroll
  for (int c = 0; c < 4; ++c) {
    bf16x8 bh, bl;
#pragma unroll
    for (int j = 0; j < 8; ++j) {
      const float wv = Wfc[(c * 32 + kg * 8 + j) * 16 + col];
      const unsigned u = __builtin_bit_cast(unsigned, wv);
      const unsigned h = u & 0xffff0000u;
      const float lof = wv - __builtin_bit_cast(float, h);
      bh[j] = (short)(h >> 16);
      bl[j] = (short)(__builtin_bit_cast(unsigned, lof) >> 16);
    }
    bhi[c] = bh;
    blo[c] = bl;
  }
  const float bb = bfc[col];

  __syncthreads();

  // xj slice in registers: row j0+col, k-slice per lane
  const int j0 = (w & 1) * 16;
  const int ih = w >> 1;
  unsigned xjr[4][8];
#pragma unroll
  for (int c = 0; c < 4; ++c) {
    const float4 v0 = *reinterpret_cast<const float4*>(&xj_s[j0 + col][c * 32 + kg * 8]);
    const float4 v1 = *reinterpret_cast<const float4*>(&xj_s[j0 + col][c * 32 + kg * 8 + 4]);
    xjr[c][0] = __builtin_bit_cast(unsigned, v0.x);
    xjr[c][1] = __builtin_bit_cast(unsigned, v0.y);
    xjr[c][2] = __builtin_bit_cast(unsigned, v0.z);
    xjr[c][3] = __builtin_bit_cast(unsigned, v0.w);
    xjr[c][4] = __builtin_bit_cast(unsigned, v1.x);
    xjr[c][5] = __builtin_bit_cast(unsigned, v1.y);
    xjr[c][6] = __builtin_bit_cast(unsigned, v1.z);
    xjr[c][7] = __builtin_bit_cast(unsigned, v1.w);
  }

  for (int i = 0; i < 16; ++i) {
    const int li = ih * 16 + i;
    const int gi = ib * 32 + li;
    f32x4 acc = {bb, bb, bb, bb};
#pragma unroll
    for (int c = 0; c < 4; ++c) {
      const float4 v0 = *reinterpret_cast<const float4*>(&xi_s[li][c * 32 + kg * 8]);
      const float4 v1 = *reinterpret_cast<const float4*>(&xi_s[li][c * 32 + kg * 8 + 4]);
      unsigned xiv[8];
      xiv[0] = __builtin_bit_cast(unsigned, v0.x);
      xiv[1] = __builtin_bit_cast(unsigned, v0.y);
      xiv[2] = __builtin_bit_cast(unsigned, v0.z);
      xiv[3] = __builtin_bit_cast(unsigned, v0.w);
      xiv[4] = __builtin_bit_cast(unsigned, v1.x);
      xiv[5] = __builtin_bit_cast(unsigned, v1.y);
      xiv[6] = __builtin_bit_cast(unsigned, v1.z);
      xiv[7] = __builtin_bit_cast(unsigned, v1.w);
      u32x4 ahv, alv;
#pragma unroll
      for (int q = 0; q < 4; ++q) {
        const float d0 = __builtin_bit_cast(float, xjr[c][2 * q]) -
                         __builtin_bit_cast(float, xiv[2 * q]);
        const float d1 = __builtin_bit_cast(float, xjr[c][2 * q + 1]) -
                         __builtin_bit_cast(float, xiv[2 * q + 1]);
        const unsigned h0 = __builtin_bit_cast(unsigned, d0) & 0x7fff0000u;
        const unsigned h1 = __builtin_bit_cast(unsigned, d1) & 0x7fff0000u;
        const float lo0 = fabsf(d0) - __builtin_bit_cast(float, h0);
        const float lo1 = fabsf(d1) - __builtin_bit_cast(float, h1);
        ahv[q] = __builtin_amdgcn_perm(h1, h0, 0x07060302u);
        alv[q] = __builtin_amdgcn_perm(__builtin_bit_cast(unsigned, lo1),
                                       __builtin_bit_cast(unsigned, lo0), 0x07060302u);
      }
      const bf16x8 ah = __builtin_bit_cast(bf16x8, ahv);
      const bf16x8 al = __builtin_bit_cast(bf16x8, alv);
      acc = __builtin_amdgcn_mfma_f32_16x16x32_bf16(ah, bhi[c], acc, 0, 0, 0);
      acc = __builtin_amdgcn_mfma_f32_16x16x32_bf16(ah, blo[c], acc, 0, 0, 0);
      acc = __builtin_amdgcn_mfma_f32_16x16x32_bf16(al, bhi[c], acc, 0, 0, 0);
    }
#pragma unroll
    for (int r = 0; r < 4; ++r) ostage[w][(kg * 4 + r) * 16 + col] = acc[r];
    const f32x4 vv = *reinterpret_cast<const f32x4*>(&ostage[w][lane * 4]);
    const int jl = lane >> 2;
    const int c0 = (lane & 3) * 4;
    const int gj = jb * 32 + j0 + jl;
    __builtin_nontemporal_store(vv, reinterpret_cast<f32x4*>(out + ((size_t)gi * 1024 + gj) * 16 + c0));
  }
}

extern "C" void kernel_launch(void* const* d_in, const int* in_sizes, int n_in,
                              void* d_out, int out_size, void* d_ws, size_t ws_size,
                              hipStream_t stream) {
  const float* feat = (const float*)d_in[0];
  const int* adj = (const int*)d_in[1];
  const float* W1 = (const float*)d_in[2];
  const float* a1 = (const float*)d_in[3];
  const float* W2 = (const float*)d_in[4];
  const float* a2 = (const float*)d_in[5];
  const float* W3 = (const float*)d_in[6];
  const float* a3 = (const float*)d_in[7];
  const float* Wfc = (const float*)d_in[8];
  const float* bfc = (const float*)d_in[9];
  float* out = (float*)d_out;

  float* ht = (float*)d_ws;        // 1024*128 (transposed H)
  float* xA = ht + 131072;         // 1024*128
  float* xB = xA + 131072;         // 1024*128

  gemm_xw_t<<<1024, 128, 0, stream>>>(feat, W1, ht);
  gat_attn<<<256, 1024, 0, stream>>>(ht, adj, a1, xA);
  gemm_xw_t<<<1024, 128, 0, stream>>>(xA, W2, ht);
  gat_attn<<<256, 1024, 0, stream>>>(ht, adj, a2, xB);
  gemm_xw_t<<<1024, 128, 0, stream>>>(xB, W3, ht);
  gat_attn<<<256, 1024, 0, stream>>>(ht, adj, a3, xA);
  edge_fc_mfma<<<1024, 256, 0, stream>>>(xA, Wfc, bfc, out);
}